// Round 9
// baseline (268.283 us; speedup 1.0000x reference)
//
#include <hip/hip_runtime.h>
#include <hip/hip_bf16.h>

// Masked SDPA, flash-attention, transposed form (S^T = K*Q^T, O^T = V^T*P^T).
// R19: TLP 2x by HALVING per-wave q-rows (16/wave). R14's occupancy attempt
// kept 32 rows/wave (156 unified regs -> 2-block residency impossible). Rows
// scale qf/oacc/sa/pf (~120 regs@32rows); 16 rows cuts ~60 -> ~96/wave, so
// __launch_bounds__(512,4) fits 4 waves/SIMD. Grid 512 (8 ab x 64 qt of 32
// rows); 8 waves = 2 qh (16 rows) x 4 sl (512 keys, 16 iters — slice geometry
// and the R11 P-skew pipeline UNCHANGED, qp-loop removed: 8+8 MFMA/iter).
// LDS 74.5 KB/block -> 2 blocks/CU (153<=160 KB) = 16 waves/CU, no extra
// rounds (512 = 256 CU x 2). Numerics bit-identical to R18 (same per-row
// slice sums, same m=0..3 merge order). Spill tripwire: WRITE_SIZE.
// prep_kv unchanged from R18 (XCD-affine, coalesced V via LDS).

#define BZ 8
#define QL 2048
#define KLEN 2048
#define DH 128
#define NSL 64          // 32-key slices per batch
#define SLICE_E 4096    // elems per slice per tensor: 512 chunks x 8 bf16
#define PPITCH 40       // P-buffer column pitch (bf16)

typedef float f32x4 __attribute__((ext_vector_type(4)));
typedef int   i32x4 __attribute__((ext_vector_type(4)));
typedef __bf16 bf16x8 __attribute__((ext_vector_type(8)));
typedef __bf16 bf16x4 __attribute__((ext_vector_type(4)));
typedef __bf16 bf16x2 __attribute__((ext_vector_type(2)));

#define QSC 0.12751879523298232f  // SCALE * log2(e); softmax in exp2 units
#define NEGV -1000000000.0f

// ---------------------------------------------------------------------------
// Prep: blocks 0..511 K-hat, 512..1023 V-hat. XCD-AFFINE remap: b = bs&7 so
// the writer block's XCD (blk%8) equals the reader's (ab = bid&7).
// K-hat chunk (kf*2+f)*64+ln holds K[s*32+f*16+lc][kf*32+qd*8+j], j=0..7
// V-hat chunk  nt*64+ln      holds V[s*32+qd*8+j][nt*16+lc]
// V path: coalesced f32x4 read of V[s*32..+31][0..127] -> LDS -> chunk emit.
// ---------------------------------------------------------------------------
__global__ void prep_kv(const float* __restrict__ kg, const float* __restrict__ vg,
                        __bf16* __restrict__ khat, __bf16* __restrict__ vhat) {
  __shared__ float vt[32][133];           // 17 KB; pad 133: read-phase 2-way (free)
  const int blk = blockIdx.x;
  const int bs = blk & 511;
  const int b = bs & 7, s = bs >> 3;      // XCD-affine: b == blk%8
  const int tid = threadIdx.x;
  if (blk < 512) {
#pragma unroll
    for (int i = 0; i < 2; ++i) {
      const int c = i * 256 + tid;        // chunk 0..511
      const int ln = c & 63, lc = ln & 15, qd = ln >> 4;
      const int ff = (c >> 6) & 1, kf = c >> 7;
      const int key = s * 32 + ff * 16 + lc;
      const float* src = kg + ((size_t)(b * KLEN + key)) * DH + kf * 32 + qd * 8;
      f32x4 a = *(const f32x4*)src;
      f32x4 d = *(const f32x4*)(src + 4);
      bf16x8 w;
      w[0]=(__bf16)a[0]; w[1]=(__bf16)a[1]; w[2]=(__bf16)a[2]; w[3]=(__bf16)a[3];
      w[4]=(__bf16)d[0]; w[5]=(__bf16)d[1]; w[6]=(__bf16)d[2]; w[7]=(__bf16)d[3];
      *(bf16x8*)&khat[((size_t)(b * 64 + s) * 512 + c) * 8] = w;
    }
  } else {
    // coalesced read: 32 rows x 128 cols = 1024 f32x4, 4 per thread
#pragma unroll
    for (int i = 0; i < 4; ++i) {
      const int u = i * 256 + tid;
      const int row = u >> 5, c4 = (u & 31) * 4;
      f32x4 a = *(const f32x4*)(vg + ((size_t)(b * KLEN + s * 32 + row)) * DH + c4);
      vt[row][c4] = a[0]; vt[row][c4 + 1] = a[1];
      vt[row][c4 + 2] = a[2]; vt[row][c4 + 3] = a[3];
    }
    __syncthreads();
#pragma unroll
    for (int i = 0; i < 2; ++i) {
      const int c = i * 256 + tid;        // chunk 0..511
      const int ln = c & 63, lc = ln & 15, qd = ln >> 4;
      const int nt = c >> 6;
      bf16x8 w;
#pragma unroll
      for (int j = 0; j < 8; ++j) w[j] = (__bf16)vt[qd * 8 + j][nt * 16 + lc];
      *(bf16x8*)&vhat[((size_t)(b * 64 + s) * 512 + c) * 8] = w;
    }
  }
}

// ---------------------------------------------------------------------------
// Main kernel. Grid 512 (ab = bid&7 XCD-L2 locality; qt = bid>>3 -> 32 q-rows),
// 512 thr = 8 waves = 2 qh (16 rows) x 4 sl (512-key range, 16 iters).
// ---------------------------------------------------------------------------
__global__ __launch_bounds__(512, 4) void fattn16(
    const __bf16* __restrict__ khat, const __bf16* __restrict__ vhat,
    const float* __restrict__ qg_, const int* __restrict__ maskg,
    float* __restrict__ outg) {
  __shared__ __align__(16) __bf16 sP[8][16 * PPITCH];   // 10 KB, wave-private
  __shared__ __align__(16) float fb[16384 + 128];       // 64.5 KB: 8 merge slots

  const int tid = threadIdx.x;
  const int wv = tid >> 6, ln = tid & 63;
  const int qd = ln >> 4, lc = ln & 15;
  const int ab = blockIdx.x & 7, qt = blockIdx.x >> 3;
  const int q0 = qt * 32;
  const int qh = wv & 1, sl = wv >> 1;

  // ---- Q fragments (B-operand), resident: 4 ksteps, pre-scaled ----
  bf16x8 qf[4];
  {
    const float* qr = qg_ + ((size_t)(ab * QL + q0 + qh * 16 + lc)) * DH + qd * 8;
#pragma unroll
    for (int kf = 0; kf < 4; ++kf) {
      f32x4 a = *(const f32x4*)(qr + kf * 32);
      f32x4 c = *(const f32x4*)(qr + kf * 32 + 4);
      bf16x8 t;
      t[0]=(__bf16)(a[0]*QSC); t[1]=(__bf16)(a[1]*QSC); t[2]=(__bf16)(a[2]*QSC); t[3]=(__bf16)(a[3]*QSC);
      t[4]=(__bf16)(c[0]*QSC); t[5]=(__bf16)(c[1]*QSC); t[6]=(__bf16)(c[2]*QSC); t[7]=(__bf16)(c[3]*QSC);
      qf[kf] = t;
    }
  }

  const __bf16* Kb = khat + (size_t)ab * NSL * SLICE_E;
  const __bf16* Vb = vhat + (size_t)ab * NSL * SLICE_E;
  const int* mrow = maskg + ab * KLEN;
  __bf16* sp0 = &sP[wv][0];

  f32x4 oacc[8];
#pragma unroll
  for (int i = 0; i < 8; ++i) oacc[i] = (f32x4){0.f, 0.f, 0.f, 0.f};
  float li = 0.f;

  // ---- pipeline state (R11 shape minus the qp dimension) ----
  bf16x8 kA[4][2], kB[4][2], vA[8];
  bf16x8 pf0;
  i32x4 mA0, mA1, mB0, mB1;
  f32x4 sa[2];
  const int s0 = sl * 16;

  auto loadK = [&](bf16x8 (&dst)[4][2], int sidx) {
    const __bf16* ks = Kb + (size_t)sidx * SLICE_E;
#pragma unroll
    for (int kf = 0; kf < 4; ++kf)
#pragma unroll
      for (int f = 0; f < 2; ++f)
        dst[kf][f] = *(const bf16x8*)&ks[((kf * 2 + f) * 64 + ln) * 8];
  };
  auto loadM = [&](i32x4& m0, i32x4& m1, int sidx) {
    m0 = *(const i32x4*)&mrow[sidx * 32 + qd * 4];
    m1 = *(const i32x4*)&mrow[sidx * 32 + 16 + qd * 4];
  };
  auto loadV = [&](int sidx) {
    const __bf16* vs = Vb + (size_t)sidx * SLICE_E;
#pragma unroll
    for (int nt = 0; nt < 8; ++nt)
      vA[nt] = *(const bf16x8*)&vs[(nt * 64 + ln) * 8];
  };
  auto qk = [&](const bf16x8 (&kk)[4][2]) {
#pragma unroll
    for (int f = 0; f < 2; ++f) sa[f] = (f32x4){0.f, 0.f, 0.f, 0.f};
#pragma unroll
    for (int kf = 0; kf < 4; ++kf)
#pragma unroll
      for (int f = 0; f < 2; ++f)
        sa[f] = __builtin_amdgcn_mfma_f32_16x16x32_bf16(kk[kf][f], qf[kf], sa[f], 0, 0, 0);
  };
  auto pv = [&]() {  // O^T += V^T P^T on operands produced one iteration ago
#pragma unroll
    for (int nt = 0; nt < 8; ++nt)
      oacc[nt] = __builtin_amdgcn_mfma_f32_16x16x32_bf16(vA[nt], pf0, oacc[nt], 0, 0, 0);
  };
  auto softmax = [&](const i32x4& m0, const i32x4& m1) {
    // p = mask ? exp2(s) : 0 ; accumulate l; P -> wave-private LDS -> pf reg.
    float ps[2][4];
#pragma unroll
    for (int r = 0; r < 4; ++r) {
      float p0 = __builtin_amdgcn_exp2f(sa[0][r]);
      float p1 = __builtin_amdgcn_exp2f(sa[1][r]);
      ps[0][r] = m0[r] ? p0 : 0.f;
      ps[1][r] = m1[r] ? p1 : 0.f;
    }
    li += ((ps[0][0] + ps[0][1]) + (ps[0][2] + ps[0][3])) +
          ((ps[1][0] + ps[1][1]) + (ps[1][2] + ps[1][3]));
#pragma unroll
    for (int f = 0; f < 2; ++f) {
      bf16x4 pw;
      pw[0] = (__bf16)ps[f][0]; pw[1] = (__bf16)ps[f][1];
      pw[2] = (__bf16)ps[f][2]; pw[3] = (__bf16)ps[f][3];
      *(bf16x4*)&sp0[lc * PPITCH + f * 16 + qd * 4] = pw;
    }
    pf0 = *(const bf16x8*)&sp0[lc * PPITCH + qd * 8];
  };

  // ---- prologue: it = 0 (QK + softmax only; V(0) -> vA for PV at it=1) ----
  loadK(kA, s0);
  loadM(mA0, mA1, s0);
  loadK(kB, s0 + 1);           // prefetch K(1)
  loadM(mB0, mB1, s0 + 1);     // prefetch mask(1)
  loadV(s0);                   // V(0)
  qk(kA);
  softmax(mA0, mA1);           // pf = P(0)

  // ---- steady: body(it) = QK(it), PV(it-1), loadV(it), softmax(it) ----
  for (int du = 0; du < 7; ++du) {
    {  // it = 2*du+1 (odd): current K in kB, prefetch into kA
      const int s = s0 + 2 * du + 1;
      loadK(kA, s + 1);
      loadM(mA0, mA1, s + 1);
      __builtin_amdgcn_s_setprio(1);
      qk(kB);
      pv();                    // V(it-1), P(it-1)
      __builtin_amdgcn_s_setprio(0);
      loadV(s);                // V(it) for next body's PV
      softmax(mB0, mB1);       // pf = P(it)
    }
    {  // it = 2*du+2 (even): current K in kA, prefetch into kB
      const int s = s0 + 2 * du + 2;
      loadK(kB, s + 1);
      loadM(mB0, mB1, s + 1);
      __builtin_amdgcn_s_setprio(1);
      qk(kA);
      pv();
      __builtin_amdgcn_s_setprio(0);
      loadV(s);
      softmax(mA0, mA1);
    }
  }
  {  // it = 15 (odd): current K in kB, no K/mask prefetch
    const int s = s0 + 15;
    __builtin_amdgcn_s_setprio(1);
    qk(kB);
    pv();                      // PV(14)
    __builtin_amdgcn_s_setprio(0);
    loadV(s);
    softmax(mB0, mB1);         // P(15)
  }
  pv();                        // PV(15) epilogue

  // ---- reduce l across the 4 key-quads ----
  li += __shfl_xor(li, 16, 64);
  li += __shfl_xor(li, 32, 64);

  // ---- ALL-WAVE flat merge: every wave publishes into slot (sl*2+qh); ONE
  //      barrier; each wave absorbs+stores 1/8 of the output (2 nt cols).
  //      Sum order per element: (((s0+s1)+s2)+s3 == R18 -> bit-identical.
  f32x4* mOv = (f32x4*)fb;
  float* sml = fb + 16384;
#pragma unroll
  for (int nt = 0; nt < 8; ++nt)
    mOv[((sl * 2 + qh) * 8 + nt) * 64 + ln] = oacc[nt];
  if (qd == 0) sml[(sl * 2 + qh) * 16 + lc] = li;
  __syncthreads();
  {
    const int qh2 = wv & 1;          // output row-group this wave stores
    const int nt0 = (wv >> 1) * 2;   // this wave's 2 nt columns
    float lsum = sml[(0 * 2 + qh2) * 16 + lc];
#pragma unroll
    for (int m = 1; m < 4; ++m) lsum += sml[(m * 2 + qh2) * 16 + lc];
    const float invL = 1.0f / lsum;
    float* orow = outg + ((size_t)(ab * QL + q0 + qh2 * 16 + lc)) * DH;
#pragma unroll
    for (int t = 0; t < 2; ++t) {
      const int nt = nt0 + t;
      f32x4 acc = mOv[((0 * 2 + qh2) * 8 + nt) * 64 + ln];
#pragma unroll
      for (int m = 1; m < 4; ++m) {
        f32x4 o2 = mOv[((m * 2 + qh2) * 8 + nt) * 64 + ln];
#pragma unroll
        for (int r = 0; r < 4; ++r) acc[r] += o2[r];
      }
      f32x4 res;
#pragma unroll
      for (int r = 0; r < 4; ++r) res[r] = acc[r] * invL;
      *(f32x4*)&orow[nt * 16 + qd * 4] = res;
    }
  }
}

// ---------------------------------------------------------------------------
// Fallback single-pass kernel (R2, proven) — used only if ws is too small.
// ---------------------------------------------------------------------------
#define KT 64
#define KPITCH 136
#define VPITCH 72
#define PPITCH2 72

__global__ __launch_bounds__(256, 1) void fattn_mono(
    const float* __restrict__ qgp, const float* __restrict__ kg,
    const float* __restrict__ vg, const int* __restrict__ maskg,
    float* __restrict__ outg) {
  __shared__ __bf16 sK[KT][KPITCH];
  __shared__ __bf16 sVT[DH][VPITCH];
  __shared__ __bf16 sPm[4][16][PPITCH2];

  const int tid = threadIdx.x;
  const int wv = tid >> 6, ln = tid & 63;
  const int qd = ln >> 4, lc = ln & 15;
  const int bid = blockIdx.x;
  const int b = bid >> 5;
  const int q0 = (bid & 31) << 6;
  const int qw = q0 + (wv << 4);

  bf16x8 qf[4];
  {
    const float* qr = qgp + ((size_t)(b * QL + qw + lc)) * DH + qd * 8;
#pragma unroll
    for (int kf = 0; kf < 4; ++kf) {
      f32x4 a = *(const f32x4*)(qr + kf * 32);
      f32x4 c = *(const f32x4*)(qr + kf * 32 + 4);
      bf16x8 t;
      t[0]=(__bf16)(a[0]*QSC); t[1]=(__bf16)(a[1]*QSC); t[2]=(__bf16)(a[2]*QSC); t[3]=(__bf16)(a[3]*QSC);
      t[4]=(__bf16)(c[0]*QSC); t[5]=(__bf16)(c[1]*QSC); t[6]=(__bf16)(c[2]*QSC); t[7]=(__bf16)(c[3]*QSC);
      qf[kf] = t;
    }
  }

  const float* kb = kg + (size_t)b * KLEN * DH;
  const float* vb = vg + (size_t)b * KLEN * DH;
  const int* mrow = maskg + b * KLEN;

  f32x4 kreg[8], va[4], vbr[4];

  auto load_tile = [&](int t) {
    const float* kt = kb + ((size_t)t * KT) * DH;
#pragma unroll
    for (int it = 0; it < 8; ++it) {
      int f = it * 256 + tid;
      kreg[it] = *(const f32x4*)(kt + (size_t)(f >> 5) * DH + (f & 31) * 4);
    }
    const float* vt = vb + ((size_t)t * KT) * DH;
#pragma unroll
    for (int it = 0; it < 4; ++it) {
      int u = it * 256 + tid;
      int m = u & 31, dc = (u >> 5) * 4;
      va[it]  = *(const f32x4*)(vt + (size_t)(2 * m) * DH + dc);
      vbr[it] = *(const f32x4*)(vt + (size_t)(2 * m + 1) * DH + dc);
    }
  };
  auto store_tile = [&]() {
#pragma unroll
    for (int it = 0; it < 8; ++it) {
      int f = it * 256 + tid;
      bf16x4 w;
      w[0]=(__bf16)kreg[it][0]; w[1]=(__bf16)kreg[it][1];
      w[2]=(__bf16)kreg[it][2]; w[3]=(__bf16)kreg[it][3];
      *(bf16x4*)&sK[f >> 5][(f & 31) * 4] = w;
    }
#pragma unroll
    for (int it = 0; it < 4; ++it) {
      int u = it * 256 + tid;
      int m = u & 31, dc = (u >> 5) * 4;
#pragma unroll
      for (int j = 0; j < 4; ++j) {
        bf16x2 p2;
        p2[0] = (__bf16)va[it][j];
        p2[1] = (__bf16)vbr[it][j];
        *(bf16x2*)&sVT[dc + j][2 * m] = p2;
      }
    }
  };

  f32x4 oacc[8];
#pragma unroll
  for (int i = 0; i < 8; ++i) oacc[i] = (f32x4){0.f, 0.f, 0.f, 0.f};
  float mi[4] = {-INFINITY, -INFINITY, -INFINITY, -INFINITY};
  float li[4] = {0.f, 0.f, 0.f, 0.f};

  load_tile(0); store_tile(); __syncthreads();

  for (int t = 0; t < (KLEN / KT); ++t) {
    const bool more = (t + 1 < (KLEN / KT));
    if (more) load_tile(t + 1);

    f32x4 sa[4];
#pragma unroll
    for (int f = 0; f < 4; ++f) sa[f] = (f32x4){0.f, 0.f, 0.f, 0.f};
#pragma unroll
    for (int kf = 0; kf < 4; ++kf)
#pragma unroll
      for (int f = 0; f < 4; ++f) {
        bf16x8 bk = *(const bf16x8*)&sK[f * 16 + lc][kf * 32 + qd * 8];
        sa[f] = __builtin_amdgcn_mfma_f32_16x16x32_bf16(qf[kf], bk, sa[f], 0, 0, 0);
      }

    const int kv0 = t * KT;
#pragma unroll
    for (int f = 0; f < 4; ++f) {
      const bool keep = mrow[kv0 + f * 16 + lc] != 0;
#pragma unroll
      for (int r = 0; r < 4; ++r) sa[f][r] = keep ? sa[f][r] : NEGV;
    }

    float rm[4], alpha[4], rs[4];
#pragma unroll
    for (int r = 0; r < 4; ++r)
      rm[r] = fmaxf(fmaxf(sa[0][r], sa[1][r]), fmaxf(sa[2][r], sa[3][r]));
#pragma unroll
    for (int sh = 0; sh < 4; ++sh) {
      const int off = 1 << sh;
#pragma unroll
      for (int r = 0; r < 4; ++r) rm[r] = fmaxf(rm[r], __shfl_xor(rm[r], off, 64));
    }
#pragma unroll
    for (int r = 0; r < 4; ++r) {
      float mn = fmaxf(mi[r], rm[r]);
      alpha[r] = __builtin_amdgcn_exp2f(mi[r] - mn);
      mi[r] = mn; rs[r] = 0.f;
    }
#pragma unroll
    for (int f = 0; f < 4; ++f)
#pragma unroll
      for (int r = 0; r < 4; ++r) {
        float p = __builtin_amdgcn_exp2f(sa[f][r] - mi[r]);
        sa[f][r] = p; rs[r] += p;
      }
#pragma unroll
    for (int sh = 0; sh < 4; ++sh) {
      const int off = 1 << sh;
#pragma unroll
      for (int r = 0; r < 4; ++r) rs[r] += __shfl_xor(rs[r], off, 64);
    }
#pragma unroll
    for (int r = 0; r < 4; ++r) li[r] = li[r] * alpha[r] + rs[r];

#pragma unroll
    for (int f = 0; f < 4; ++f)
#pragma unroll
      for (int r = 0; r < 4; ++r)
        sPm[wv][qd * 4 + r][f * 16 + lc] = (__bf16)sa[f][r];
#pragma unroll
    for (int nt = 0; nt < 8; ++nt)
#pragma unroll
      for (int r = 0; r < 4; ++r) oacc[nt][r] *= alpha[r];

#pragma unroll
    for (int kp = 0; kp < 2; ++kp) {
      bf16x8 ap = *(const bf16x8*)&sPm[wv][lc][kp * 32 + qd * 8];
#pragma unroll
      for (int nt = 0; nt < 8; ++nt) {
        bf16x8 bv = *(const bf16x8*)&sVT[nt * 16 + lc][kp * 32 + qd * 8];
        oacc[nt] = __builtin_amdgcn_mfma_f32_16x16x32_bf16(ap, bv, oacc[nt], 0, 0, 0);
      }
    }

    __syncthreads();
    if (more) store_tile();
    __syncthreads();
  }

  float inv[4];
#pragma unroll
  for (int r = 0; r < 4; ++r) inv[r] = 1.0f / li[r];
  float* orow = outg + ((size_t)(b * QL + qw)) * DH;
#pragma unroll
  for (int nt = 0; nt < 8; ++nt)
#pragma unroll
    for (int r = 0; r < 4; ++r)
      orow[(size_t)(qd * 4 + r) * DH + nt * 16 + lc] = oacc[nt][r] * inv[r];
}

extern "C" void kernel_launch(void* const* d_in, const int* in_sizes, int n_in,
                              void* d_out, int out_size, void* d_ws, size_t ws_size,
                              hipStream_t stream) {
  (void)in_sizes; (void)n_in; (void)out_size;
  const float* q = (const float*)d_in[0];
  const float* k = (const float*)d_in[1];
  const float* v = (const float*)d_in[2];
  const int* mask = (const int*)d_in[3];
  float* out = (float*)d_out;

  const size_t kv_elems = (size_t)BZ * KLEN * DH;  // per tensor (4 MiB as bf16)
  if (ws_size >= 2 * kv_elems * sizeof(__bf16)) {
    __bf16* khat = (__bf16*)d_ws;
    __bf16* vhat = khat + kv_elems;
    prep_kv<<<dim3(1024), dim3(256), 0, stream>>>(k, v, khat, vhat);
    fattn16<<<dim3(512), dim3(512), 0, stream>>>(khat, vhat, q, mask, out);
  } else {
    fattn_mono<<<dim3(BZ * (QL / 64)), dim3(256), 0, stream>>>(q, k, v, mask, out);
  }
}

// Round 10
// 102.104 us; speedup vs baseline: 2.6275x; 2.6275x over previous
//
#include <hip/hip_runtime.h>
#include <hip/hip_bf16.h>

// Masked SDPA, flash-attention, transposed form (S^T = K*Q^T, O^T = V^T*P^T).
// R20: REVERT to R18 (proven best: 102.48us total). R19's launch_bounds(512,4)
// forced 64 VGPRs against ~150 live regs -> scratch spill (WRITE 530MB, FETCH
// 345MB from L2 pollution) -> 2.6x regression. TLP axis now closed on all
// fronts: 4 w/SIMD spills (R19), block-split costs a round (+8us, R14), 3
// w/SIMD unreachable with 8-wave blocks and pointless with 4-wave blocks
// (total work = 2048 waves = 8/CU fixed). Session ledger of closed axes:
// bytes (R12 neutral), alignment (R15 neutral), +regs (R13 spill), TLP (R14/
// R19), sync (R15), epilogue (R16-R18 captured, -2.2us). Body is issue/chain-
// bound at 2 waves/SIMD; register file jails occupancy; remaining total is
// harness fill/launch overhead. This is the structural ceiling configuration.
// Grid 256 x 512 thr: 8 waves = 2 q-groups (32 rows) x 4 kv-slices (512 keys).

#define BZ 8
#define QL 2048
#define KLEN 2048
#define DH 128
#define NSL 64          // 32-key slices per batch
#define SLICE_E 4096    // elems per slice per tensor: 512 chunks x 8 bf16
#define PPITCH 40       // P-buffer column pitch (bf16)

typedef float f32x4 __attribute__((ext_vector_type(4)));
typedef int   i32x4 __attribute__((ext_vector_type(4)));
typedef __bf16 bf16x8 __attribute__((ext_vector_type(8)));
typedef __bf16 bf16x4 __attribute__((ext_vector_type(4)));
typedef __bf16 bf16x2 __attribute__((ext_vector_type(2)));

#define QSC 0.12751879523298232f  // SCALE * log2(e); softmax in exp2 units
#define NEGV -1000000000.0f

// ---------------------------------------------------------------------------
// Prep: blocks 0..511 K-hat, 512..1023 V-hat. XCD-AFFINE remap: b = bs&7 so
// the writer block's XCD (blk%8) equals the reader's (ab = bid&7).
// K-hat chunk (kf*2+f)*64+ln holds K[s*32+f*16+lc][kf*32+qd*8+j], j=0..7
// V-hat chunk  nt*64+ln      holds V[s*32+qd*8+j][nt*16+lc]
// V path: coalesced f32x4 read of V[s*32..+31][0..127] -> LDS -> chunk emit.
// ---------------------------------------------------------------------------
__global__ void prep_kv(const float* __restrict__ kg, const float* __restrict__ vg,
                        __bf16* __restrict__ khat, __bf16* __restrict__ vhat) {
  __shared__ float vt[32][133];           // 17 KB; pad 133: read-phase 2-way (free)
  const int blk = blockIdx.x;
  const int bs = blk & 511;
  const int b = bs & 7, s = bs >> 3;      // XCD-affine: b == blk%8
  const int tid = threadIdx.x;
  if (blk < 512) {
#pragma unroll
    for (int i = 0; i < 2; ++i) {
      const int c = i * 256 + tid;        // chunk 0..511
      const int ln = c & 63, lc = ln & 15, qd = ln >> 4;
      const int ff = (c >> 6) & 1, kf = c >> 7;
      const int key = s * 32 + ff * 16 + lc;
      const float* src = kg + ((size_t)(b * KLEN + key)) * DH + kf * 32 + qd * 8;
      f32x4 a = *(const f32x4*)src;
      f32x4 d = *(const f32x4*)(src + 4);
      bf16x8 w;
      w[0]=(__bf16)a[0]; w[1]=(__bf16)a[1]; w[2]=(__bf16)a[2]; w[3]=(__bf16)a[3];
      w[4]=(__bf16)d[0]; w[5]=(__bf16)d[1]; w[6]=(__bf16)d[2]; w[7]=(__bf16)d[3];
      *(bf16x8*)&khat[((size_t)(b * 64 + s) * 512 + c) * 8] = w;
    }
  } else {
    // coalesced read: 32 rows x 128 cols = 1024 f32x4, 4 per thread
#pragma unroll
    for (int i = 0; i < 4; ++i) {
      const int u = i * 256 + tid;
      const int row = u >> 5, c4 = (u & 31) * 4;
      f32x4 a = *(const f32x4*)(vg + ((size_t)(b * KLEN + s * 32 + row)) * DH + c4);
      vt[row][c4] = a[0]; vt[row][c4 + 1] = a[1];
      vt[row][c4 + 2] = a[2]; vt[row][c4 + 3] = a[3];
    }
    __syncthreads();
#pragma unroll
    for (int i = 0; i < 2; ++i) {
      const int c = i * 256 + tid;        // chunk 0..511
      const int ln = c & 63, lc = ln & 15, qd = ln >> 4;
      const int nt = c >> 6;
      bf16x8 w;
#pragma unroll
      for (int j = 0; j < 8; ++j) w[j] = (__bf16)vt[qd * 8 + j][nt * 16 + lc];
      *(bf16x8*)&vhat[((size_t)(b * 64 + s) * 512 + c) * 8] = w;
    }
  }
}

// ---------------------------------------------------------------------------
// Main kernel. Grid 256 (ab = bid&7 XCD-L2 locality; qt = bid>>3 -> 64 q-rows),
// 512 thr = 8 waves. qg = wv&1 (32 q-rows), sl = wv>>1 (512-key range, 16 iters).
// ---------------------------------------------------------------------------
__global__ __launch_bounds__(512, 2) void fattn15(
    const __bf16* __restrict__ khat, const __bf16* __restrict__ vhat,
    const float* __restrict__ qg_, const int* __restrict__ maskg,
    float* __restrict__ outg) {
  __shared__ __align__(16) __bf16 sP[8][2][16 * PPITCH];  // 20 KB, wave-private
  __shared__ __align__(16) float fb[32768 + 256];         // 129 KB: 4 merge slots

  const int tid = threadIdx.x;
  const int wv = tid >> 6, ln = tid & 63;
  const int qd = ln >> 4, lc = ln & 15;
  const int ab = blockIdx.x & 7, qt = blockIdx.x >> 3;
  const int q0 = qt * 64;
  const int qg = wv & 1, sl = wv >> 1;

  // ---- Q fragments (B-operand), resident: 2 qp x 4 ksteps, pre-scaled ----
  bf16x8 qf[2][4];
#pragma unroll
  for (int qp = 0; qp < 2; ++qp) {
    const float* qr = qg_ + ((size_t)(ab * QL + q0 + qg * 32 + qp * 16 + lc)) * DH + qd * 8;
#pragma unroll
    for (int kf = 0; kf < 4; ++kf) {
      f32x4 a = *(const f32x4*)(qr + kf * 32);
      f32x4 c = *(const f32x4*)(qr + kf * 32 + 4);
      bf16x8 t;
      t[0]=(__bf16)(a[0]*QSC); t[1]=(__bf16)(a[1]*QSC); t[2]=(__bf16)(a[2]*QSC); t[3]=(__bf16)(a[3]*QSC);
      t[4]=(__bf16)(c[0]*QSC); t[5]=(__bf16)(c[1]*QSC); t[6]=(__bf16)(c[2]*QSC); t[7]=(__bf16)(c[3]*QSC);
      qf[qp][kf] = t;
    }
  }

  const __bf16* Kb = khat + (size_t)ab * NSL * SLICE_E;
  const __bf16* Vb = vhat + (size_t)ab * NSL * SLICE_E;
  const int* mrow = maskg + ab * KLEN;
  __bf16* sp0 = &sP[wv][0][0];
  __bf16* sp1 = &sP[wv][1][0];

  f32x4 oacc[2][8];
#pragma unroll
  for (int qp = 0; qp < 2; ++qp)
#pragma unroll
    for (int i = 0; i < 8; ++i) oacc[qp][i] = (f32x4){0.f, 0.f, 0.f, 0.f};
  float li[2] = {0.f, 0.f};

  // ---- pipeline state (identical footprint to R11) ----
  bf16x8 kA[4][2], kB[4][2], vA[8];
  bf16x8 pf0, pf1;
  i32x4 mA0, mA1, mB0, mB1;
  f32x4 sa[2][2];
  const int s0 = sl * 16;

  auto loadK = [&](bf16x8 (&dst)[4][2], int sidx) {
    const __bf16* ks = Kb + (size_t)sidx * SLICE_E;
#pragma unroll
    for (int kf = 0; kf < 4; ++kf)
#pragma unroll
      for (int f = 0; f < 2; ++f)
        dst[kf][f] = *(const bf16x8*)&ks[((kf * 2 + f) * 64 + ln) * 8];
  };
  auto loadM = [&](i32x4& m0, i32x4& m1, int sidx) {
    m0 = *(const i32x4*)&mrow[sidx * 32 + qd * 4];
    m1 = *(const i32x4*)&mrow[sidx * 32 + 16 + qd * 4];
  };
  auto loadV = [&](int sidx) {
    const __bf16* vs = Vb + (size_t)sidx * SLICE_E;
#pragma unroll
    for (int nt = 0; nt < 8; ++nt)
      vA[nt] = *(const bf16x8*)&vs[(nt * 64 + ln) * 8];
  };
  auto qk = [&](const bf16x8 (&kk)[4][2]) {
#pragma unroll
    for (int f = 0; f < 2; ++f)
#pragma unroll
      for (int qp = 0; qp < 2; ++qp) sa[f][qp] = (f32x4){0.f, 0.f, 0.f, 0.f};
#pragma unroll
    for (int kf = 0; kf < 4; ++kf)
#pragma unroll
      for (int f = 0; f < 2; ++f) {
        sa[f][0] = __builtin_amdgcn_mfma_f32_16x16x32_bf16(kk[kf][f], qf[0][kf], sa[f][0], 0, 0, 0);
        sa[f][1] = __builtin_amdgcn_mfma_f32_16x16x32_bf16(kk[kf][f], qf[1][kf], sa[f][1], 0, 0, 0);
      }
  };
  auto pv = [&]() {  // O^T += V^T P^T on operands produced one iteration ago
#pragma unroll
    for (int nt = 0; nt < 8; ++nt) {
      oacc[0][nt] = __builtin_amdgcn_mfma_f32_16x16x32_bf16(vA[nt], pf0, oacc[0][nt], 0, 0, 0);
      oacc[1][nt] = __builtin_amdgcn_mfma_f32_16x16x32_bf16(vA[nt], pf1, oacc[1][nt], 0, 0, 0);
    }
  };
  auto softmax = [&](const i32x4& m0, const i32x4& m1) {
    // p = mask ? exp2(s) : 0 ; accumulate l; P -> wave-private LDS -> pf regs.
    // pf consumed by PV one iteration later, so the lgkm wait is off-path.
#pragma unroll
    for (int qp = 0; qp < 2; ++qp) {
      float ps[2][4];
#pragma unroll
      for (int r = 0; r < 4; ++r) {
        float p0 = __builtin_amdgcn_exp2f(sa[0][qp][r]);
        float p1 = __builtin_amdgcn_exp2f(sa[1][qp][r]);
        ps[0][r] = m0[r] ? p0 : 0.f;
        ps[1][r] = m1[r] ? p1 : 0.f;
      }
      li[qp] += ((ps[0][0] + ps[0][1]) + (ps[0][2] + ps[0][3])) +
                ((ps[1][0] + ps[1][1]) + (ps[1][2] + ps[1][3]));
      __bf16* sp = (qp == 0) ? sp0 : sp1;
#pragma unroll
      for (int f = 0; f < 2; ++f) {
        bf16x4 pw;
        pw[0] = (__bf16)ps[f][0]; pw[1] = (__bf16)ps[f][1];
        pw[2] = (__bf16)ps[f][2]; pw[3] = (__bf16)ps[f][3];
        *(bf16x4*)&sp[lc * PPITCH + f * 16 + qd * 4] = pw;
      }
    }
    pf0 = *(const bf16x8*)&sp0[lc * PPITCH + qd * 8];
    pf1 = *(const bf16x8*)&sp1[lc * PPITCH + qd * 8];
  };

  // ---- prologue: it = 0 (QK + softmax only; V(0) -> vA for PV at it=1) ----
  loadK(kA, s0);
  loadM(mA0, mA1, s0);
  loadK(kB, s0 + 1);           // prefetch K(1)
  loadM(mB0, mB1, s0 + 1);     // prefetch mask(1)
  loadV(s0);                   // V(0)
  qk(kA);
  softmax(mA0, mA1);           // pf = P(0)

  // ---- steady: body(it) = QK(it), PV(it-1), loadV(it), softmax(it) ----
  for (int du = 0; du < 7; ++du) {
    {  // it = 2*du+1 (odd): current K in kB, prefetch into kA
      const int s = s0 + 2 * du + 1;
      loadK(kA, s + 1);
      loadM(mA0, mA1, s + 1);
      __builtin_amdgcn_s_setprio(1);
      qk(kB);
      pv();                    // V(it-1), P(it-1)
      __builtin_amdgcn_s_setprio(0);
      loadV(s);                // V(it) for next body's PV
      softmax(mB0, mB1);       // pf = P(it)
    }
    {  // it = 2*du+2 (even): current K in kA, prefetch into kB
      const int s = s0 + 2 * du + 2;
      loadK(kB, s + 1);
      loadM(mB0, mB1, s + 1);
      __builtin_amdgcn_s_setprio(1);
      qk(kA);
      pv();
      __builtin_amdgcn_s_setprio(0);
      loadV(s);
      softmax(mA0, mA1);
    }
  }
  {  // it = 15 (odd): current K in kB, no K/mask prefetch
    const int s = s0 + 15;
    __builtin_amdgcn_s_setprio(1);
    qk(kB);
    pv();                      // PV(14)
    __builtin_amdgcn_s_setprio(0);
    loadV(s);
    softmax(mB0, mB1);         // P(15)
  }
  pv();                        // PV(15) epilogue

  // ---- reduce l across the 4 key-quads ----
#pragma unroll
  for (int qp = 0; qp < 2; ++qp) {
    li[qp] += __shfl_xor(li[qp], 16, 64);
    li[qp] += __shfl_xor(li[qp], 32, 64);
  }

  // ---- ALL-WAVE flat merge: every slice publishes into slot sl; ONE barrier;
  //      each wave absorbs+stores 1/8 of the output (2 nt cols x both qp).
  //      Sum order per element: ((s0+s1)+s2)+s3 -> bit-identical to R17/R18.
  f32x4* mOv = (f32x4*)fb;
  float* sml = fb + 32768;
#pragma unroll
  for (int qp = 0; qp < 2; ++qp) {
#pragma unroll
    for (int nt = 0; nt < 8; ++nt)
      mOv[(((sl * 2 + qp) * 2 + qg) * 8 + nt) * 64 + ln] = oacc[qp][nt];
    if (qd == 0) sml[((sl * 2 + qp) * 2 + qg) * 16 + lc] = li[qp];
  }
  __syncthreads();
  {
    const int qg2 = wv & 1;          // output row-group this wave stores
    const int nt0 = (wv >> 1) * 2;   // this wave's 2 nt columns
#pragma unroll
    for (int qp = 0; qp < 2; ++qp) {
      float lsum = sml[((0 * 2 + qp) * 2 + qg2) * 16 + lc];
#pragma unroll
      for (int m = 1; m < 4; ++m) lsum += sml[((m * 2 + qp) * 2 + qg2) * 16 + lc];
      const float invL = 1.0f / lsum;
      float* orow = outg + ((size_t)(ab * QL + q0 + qg2 * 32 + qp * 16 + lc)) * DH;
#pragma unroll
      for (int t = 0; t < 2; ++t) {
        const int nt = nt0 + t;
        f32x4 acc = mOv[(((0 * 2 + qp) * 2 + qg2) * 8 + nt) * 64 + ln];
#pragma unroll
        for (int m = 1; m < 4; ++m) {
          f32x4 o2 = mOv[(((m * 2 + qp) * 2 + qg2) * 8 + nt) * 64 + ln];
#pragma unroll
          for (int r = 0; r < 4; ++r) acc[r] += o2[r];
        }
        f32x4 res;
#pragma unroll
        for (int r = 0; r < 4; ++r) res[r] = acc[r] * invL;
        *(f32x4*)&orow[nt * 16 + qd * 4] = res;
      }
    }
  }
}

// ---------------------------------------------------------------------------
// Fallback single-pass kernel (R2, proven) — used only if ws is too small.
// ---------------------------------------------------------------------------
#define KT 64
#define KPITCH 136
#define VPITCH 72
#define PPITCH2 72

__global__ __launch_bounds__(256, 1) void fattn_mono(
    const float* __restrict__ qgp, const float* __restrict__ kg,
    const float* __restrict__ vg, const int* __restrict__ maskg,
    float* __restrict__ outg) {
  __shared__ __bf16 sK[KT][KPITCH];
  __shared__ __bf16 sVT[DH][VPITCH];
  __shared__ __bf16 sPm[4][16][PPITCH2];

  const int tid = threadIdx.x;
  const int wv = tid >> 6, ln = tid & 63;
  const int qd = ln >> 4, lc = ln & 15;
  const int bid = blockIdx.x;
  const int b = bid >> 5;
  const int q0 = (bid & 31) << 6;
  const int qw = q0 + (wv << 4);

  bf16x8 qf[4];
  {
    const float* qr = qgp + ((size_t)(b * QL + qw + lc)) * DH + qd * 8;
#pragma unroll
    for (int kf = 0; kf < 4; ++kf) {
      f32x4 a = *(const f32x4*)(qr + kf * 32);
      f32x4 c = *(const f32x4*)(qr + kf * 32 + 4);
      bf16x8 t;
      t[0]=(__bf16)(a[0]*QSC); t[1]=(__bf16)(a[1]*QSC); t[2]=(__bf16)(a[2]*QSC); t[3]=(__bf16)(a[3]*QSC);
      t[4]=(__bf16)(c[0]*QSC); t[5]=(__bf16)(c[1]*QSC); t[6]=(__bf16)(c[2]*QSC); t[7]=(__bf16)(c[3]*QSC);
      qf[kf] = t;
    }
  }

  const float* kb = kg + (size_t)b * KLEN * DH;
  const float* vb = vg + (size_t)b * KLEN * DH;
  const int* mrow = maskg + b * KLEN;

  f32x4 kreg[8], va[4], vbr[4];

  auto load_tile = [&](int t) {
    const float* kt = kb + ((size_t)t * KT) * DH;
#pragma unroll
    for (int it = 0; it < 8; ++it) {
      int f = it * 256 + tid;
      kreg[it] = *(const f32x4*)(kt + (size_t)(f >> 5) * DH + (f & 31) * 4);
    }
    const float* vt = vb + ((size_t)t * KT) * DH;
#pragma unroll
    for (int it = 0; it < 4; ++it) {
      int u = it * 256 + tid;
      int m = u & 31, dc = (u >> 5) * 4;
      va[it]  = *(const f32x4*)(vt + (size_t)(2 * m) * DH + dc);
      vbr[it] = *(const f32x4*)(vt + (size_t)(2 * m + 1) * DH + dc);
    }
  };
  auto store_tile = [&]() {
#pragma unroll
    for (int it = 0; it < 8; ++it) {
      int f = it * 256 + tid;
      bf16x4 w;
      w[0]=(__bf16)kreg[it][0]; w[1]=(__bf16)kreg[it][1];
      w[2]=(__bf16)kreg[it][2]; w[3]=(__bf16)kreg[it][3];
      *(bf16x4*)&sK[f >> 5][(f & 31) * 4] = w;
    }
#pragma unroll
    for (int it = 0; it < 4; ++it) {
      int u = it * 256 + tid;
      int m = u & 31, dc = (u >> 5) * 4;
#pragma unroll
      for (int j = 0; j < 4; ++j) {
        bf16x2 p2;
        p2[0] = (__bf16)va[it][j];
        p2[1] = (__bf16)vbr[it][j];
        *(bf16x2*)&sVT[dc + j][2 * m] = p2;
      }
    }
  };

  f32x4 oacc[8];
#pragma unroll
  for (int i = 0; i < 8; ++i) oacc[i] = (f32x4){0.f, 0.f, 0.f, 0.f};
  float mi[4] = {-INFINITY, -INFINITY, -INFINITY, -INFINITY};
  float li[4] = {0.f, 0.f, 0.f, 0.f};

  load_tile(0); store_tile(); __syncthreads();

  for (int t = 0; t < (KLEN / KT); ++t) {
    const bool more = (t + 1 < (KLEN / KT));
    if (more) load_tile(t + 1);

    f32x4 sa[4];
#pragma unroll
    for (int f = 0; f < 4; ++f) sa[f] = (f32x4){0.f, 0.f, 0.f, 0.f};
#pragma unroll
    for (int kf = 0; kf < 4; ++kf)
#pragma unroll
      for (int f = 0; f < 4; ++f) {
        bf16x8 bk = *(const bf16x8*)&sK[f * 16 + lc][kf * 32 + qd * 8];
        sa[f] = __builtin_amdgcn_mfma_f32_16x16x32_bf16(qf[kf], bk, sa[f], 0, 0, 0);
      }

    const int kv0 = t * KT;
#pragma unroll
    for (int f = 0; f < 4; ++f) {
      const bool keep = mrow[kv0 + f * 16 + lc] != 0;
#pragma unroll
      for (int r = 0; r < 4; ++r) sa[f][r] = keep ? sa[f][r] : NEGV;
    }

    float rm[4], alpha[4], rs[4];
#pragma unroll
    for (int r = 0; r < 4; ++r)
      rm[r] = fmaxf(fmaxf(sa[0][r], sa[1][r]), fmaxf(sa[2][r], sa[3][r]));
#pragma unroll
    for (int sh = 0; sh < 4; ++sh) {
      const int off = 1 << sh;
#pragma unroll
      for (int r = 0; r < 4; ++r) rm[r] = fmaxf(rm[r], __shfl_xor(rm[r], off, 64));
    }
#pragma unroll
    for (int r = 0; r < 4; ++r) {
      float mn = fmaxf(mi[r], rm[r]);
      alpha[r] = __builtin_amdgcn_exp2f(mi[r] - mn);
      mi[r] = mn; rs[r] = 0.f;
    }
#pragma unroll
    for (int f = 0; f < 4; ++f)
#pragma unroll
      for (int r = 0; r < 4; ++r) {
        float p = __builtin_amdgcn_exp2f(sa[f][r] - mi[r]);
        sa[f][r] = p; rs[r] += p;
      }
#pragma unroll
    for (int sh = 0; sh < 4; ++sh) {
      const int off = 1 << sh;
#pragma unroll
      for (int r = 0; r < 4; ++r) rs[r] += __shfl_xor(rs[r], off, 64);
    }
#pragma unroll
    for (int r = 0; r < 4; ++r) li[r] = li[r] * alpha[r] + rs[r];

#pragma unroll
    for (int f = 0; f < 4; ++f)
#pragma unroll
      for (int r = 0; r < 4; ++r)
        sPm[wv][qd * 4 + r][f * 16 + lc] = (__bf16)sa[f][r];
#pragma unroll
    for (int nt = 0; nt < 8; ++nt)
#pragma unroll
      for (int r = 0; r < 4; ++r) oacc[nt][r] *= alpha[r];

#pragma unroll
    for (int kp = 0; kp < 2; ++kp) {
      bf16x8 ap = *(const bf16x8*)&sPm[wv][lc][kp * 32 + qd * 8];
#pragma unroll
      for (int nt = 0; nt < 8; ++nt) {
        bf16x8 bv = *(const bf16x8*)&sVT[nt * 16 + lc][kp * 32 + qd * 8];
        oacc[nt] = __builtin_amdgcn_mfma_f32_16x16x32_bf16(ap, bv, oacc[nt], 0, 0, 0);
      }
    }

    __syncthreads();
    if (more) store_tile();
    __syncthreads();
  }

  float inv[4];
#pragma unroll
  for (int r = 0; r < 4; ++r) inv[r] = 1.0f / li[r];
  float* orow = outg + ((size_t)(b * QL + qw)) * DH;
#pragma unroll
  for (int nt = 0; nt < 8; ++nt)
#pragma unroll
    for (int r = 0; r < 4; ++r)
      orow[(size_t)(qd * 4 + r) * DH + nt * 16 + lc] = oacc[nt][r] * inv[r];
}

extern "C" void kernel_launch(void* const* d_in, const int* in_sizes, int n_in,
                              void* d_out, int out_size, void* d_ws, size_t ws_size,
                              hipStream_t stream) {
  (void)in_sizes; (void)n_in; (void)out_size;
  const float* q = (const float*)d_in[0];
  const float* k = (const float*)d_in[1];
  const float* v = (const float*)d_in[2];
  const int* mask = (const int*)d_in[3];
  float* out = (float*)d_out;

  const size_t kv_elems = (size_t)BZ * KLEN * DH;  // per tensor (4 MiB as bf16)
  if (ws_size >= 2 * kv_elems * sizeof(__bf16)) {
    __bf16* khat = (__bf16*)d_ws;
    __bf16* vhat = khat + kv_elems;
    prep_kv<<<dim3(1024), dim3(256), 0, stream>>>(k, v, khat, vhat);
    fattn15<<<dim3(256), dim3(512), 0, stream>>>(khat, vhat, q, mask, out);
  } else {
    fattn_mono<<<dim3(BZ * (QL / 64)), dim3(256), 0, stream>>>(q, k, v, mask, out);
  }
}